// Round 1
// baseline (202.057 us; speedup 1.0000x reference)
//
#include <hip/hip_runtime.h>
#include <cstdio>

#define HID 64
#define D 128            // 2*HID
#define NUM_REL 230
#define NUM_TS 365
#define NCOMB (NUM_REL*NUM_TS)   // 83950
#define SLOPE 0.2f
#define XPAD 136         // LDS row stride in bf16 (272 B -> 2-way bank alias, free)
#define MAXDEG 64        // Poisson(8) max degree ~25; P(deg>=64) < 1e-40

typedef __attribute__((ext_vector_type(8))) short short8;
typedef __attribute__((ext_vector_type(4))) float f32x4;

__device__ __forceinline__ float lrelu(float v){ return v >= 0.f ? v : SLOPE*v; }

// bf16 helpers
__device__ __forceinline__ unsigned bf_rne(float f){
    unsigned u = __float_as_uint(f);
    return (u + 0x7fffu + ((u >> 16) & 1u)) >> 16;
}
__device__ __forceinline__ unsigned pk2(float a, float b){
    return bf_rne(a) | (bf_rne(b) << 16);
}
__device__ __forceinline__ float bf_lo(unsigned u){ return __uint_as_float(u << 16); }
__device__ __forceinline__ float bf_hi(unsigned u){ return __uint_as_float(u & 0xffff0000u); }

// ---------------------------------------------------------------------------
// Launch 2 — k_prep: parts (relP/timP) + W-pack + edge bucket-scatter.
// blocks [0,298)        : relP/timP rows (2 rows per block)
// blocks [298,322)      : pack W13^T / W2^T into MFMA A-frag order (bf16)
// blocks [322,322+NE256): slot = atomicAdd(deg[dst]); ebuf[dst*MAXDEG+slot]
// ---------------------------------------------------------------------------
__global__ __launch_bounds__(256) void k_prep(
        const float* __restrict__ rel_table, const float* __restrict__ time_table,
        const float* __restrict__ W_rt, const float* __restrict__ W_fc,
        const int* __restrict__ edges, int n_edges,
        float* __restrict__ relP, float* __restrict__ timP,
        unsigned short* __restrict__ Wpk13, unsigned short* __restrict__ Wpk2,
        int* __restrict__ deg, int2* __restrict__ ebuf)
{
    int b = blockIdx.x;
    if (b < 298) {
        int row = b*2 + (threadIdx.x >> 7);
        int j   = threadIdx.x & 127;
        if (row >= NUM_REL + NUM_TS) return;
        const float* tbl; const float* Wb; float* out;
        if (row < NUM_REL) { tbl = rel_table + row*HID;            Wb = W_rt;          out = relP + row*D; }
        else               { tbl = time_table + (row-NUM_REL)*HID; Wb = W_rt + HID*D;  out = timP + (row-NUM_REL)*D; }
        float acc = 0.f;
        #pragma unroll
        for (int k = 0; k < HID; ++k) acc += tbl[k] * Wb[k*D + j];
        out[j] = acc;
    } else if (b < 322) {
        int id = (b - 298)*256 + threadIdx.x;   // 0..6143
        if (id < 4096) {                 // W13 frags
            int mt = id >> 8;            // 0..15
            int s  = (id >> 6) & 3;
            int l  = id & 63;
            int m  = mt*16 + (l & 15);   // output col 0..255
            int kb = s*32 + (l >> 4)*8;
            unsigned short* dst = Wpk13 + ((size_t)(mt*4 + s)*64 + l)*8;
            #pragma unroll
            for (int j = 0; j < 8; ++j) {
                int k = kb + j;
                float v = (m < D) ? W_fc[(size_t)k*D + m]
                                  : W_fc[(size_t)(256 + k)*D + (m - D)];
                dst[j] = (unsigned short)bf_rne(v);
            }
        } else {                         // W2 frags
            int id2 = id - 4096;
            int mt = id2 >> 8;           // 0..7
            int s  = (id2 >> 6) & 3;
            int l  = id2 & 63;
            int m  = mt*16 + (l & 15);
            int kb = s*32 + (l >> 4)*8;
            unsigned short* dst = Wpk2 + ((size_t)(mt*4 + s)*64 + l)*8;
            #pragma unroll
            for (int j = 0; j < 8; ++j) {
                int k = kb + j;
                dst[j] = (unsigned short)bf_rne(W_fc[(size_t)(D + k)*D + m]);
            }
        }
    } else {
        int e = (b - 322)*256 + threadIdx.x;
        if (e < n_edges) {
            int4 ed = ((const int4*)edges)[e];
            int slot = atomicAdd(&deg[ed.y], 1);
            if (slot < MAXDEG)   // safety clamp; statistically never taken
                ebuf[(size_t)ed.y*MAXDEG + slot] = make_int2(ed.x, ed.z*NUM_TS + ed.w);
        }
    }
}

// ---------------------------------------------------------------------------
// Launch 3 — k_mm: xw MFMA blocks + t2 MFMA blocks, one grid.
// ---------------------------------------------------------------------------
__device__ __forceinline__ void xw_body(
        int xb, const float* __restrict__ x,
        const unsigned short* __restrict__ Wpk13,
        unsigned short* __restrict__ xW13bf, int n_nodes,
        unsigned short* Xs /* 64*XPAD */)
{
    int t = threadIdx.x;
    int nodeBase = xb*64;
    {   // stage X tile (fp32 -> bf16), 4 threads per node row
        int row = t >> 2;
        int k0  = (t & 3)*32;
        int node = nodeBase + row;
        unsigned short* dst = Xs + row*XPAD + k0;
        if (node < n_nodes) {
            const float4* src = (const float4*)(x + (size_t)node*D + k0);
            #pragma unroll
            for (int g = 0; g < 8; ++g) {
                float4 v = src[g];
                *(uint2*)(dst + g*4) = make_uint2(pk2(v.x, v.y), pk2(v.z, v.w));
            }
        } else {
            #pragma unroll
            for (int g = 0; g < 8; ++g)
                *(uint2*)(dst + g*4) = make_uint2(0u, 0u);
        }
    }
    __syncthreads();

    int w = t >> 6, l = t & 63;
    int li = l & 15, q = l >> 4;

    f32x4 acc[4][4];
    #pragma unroll
    for (int mi = 0; mi < 4; ++mi)
        #pragma unroll
        for (int ni = 0; ni < 4; ++ni) acc[mi][ni] = (f32x4){0.f,0.f,0.f,0.f};

    #pragma unroll 1
    for (int s = 0; s < 4; ++s) {
        short8 af[4], bf[4];
        #pragma unroll
        for (int mi = 0; mi < 4; ++mi) {
            int mt = w*4 + mi;
            af[mi] = *(const short8*)(Wpk13 + ((size_t)(mt*4 + s)*64 + l)*8);
        }
        #pragma unroll
        for (int ni = 0; ni < 4; ++ni)
            bf[ni] = *(const short8*)(Xs + (ni*16 + li)*XPAD + s*32 + q*8);
        #pragma unroll
        for (int mi = 0; mi < 4; ++mi)
            #pragma unroll
            for (int ni = 0; ni < 4; ++ni)
                acc[mi][ni] = __builtin_amdgcn_mfma_f32_16x16x32_bf16(
                                  af[mi], bf[ni], acc[mi][ni], 0, 0, 0);
    }
    #pragma unroll
    for (int ni = 0; ni < 4; ++ni) {
        int node = nodeBase + ni*16 + li;
        if (node >= n_nodes) continue;
        #pragma unroll
        for (int mi = 0; mi < 4; ++mi) {
            int col = w*64 + mi*16 + q*4;
            *(uint2*)(xW13bf + (size_t)node*256 + col) =
                make_uint2(pk2(acc[mi][ni][0], acc[mi][ni][1]),
                           pk2(acc[mi][ni][2], acc[mi][ni][3]));
        }
    }
}

__device__ __forceinline__ void t2_body(
        int tb, const float* __restrict__ relP, const float* __restrict__ timP,
        const float* __restrict__ b_rt, const unsigned short* __restrict__ Wpk2,
        unsigned short* __restrict__ T2bf,
        unsigned short* Hs /* 128*XPAD */)
{
    int t = threadIdx.x;
    int cBase = tb*128;
    {   // stage H tile: compute lrelu(relP+timP+b) -> bf16, 2 threads per row
        int r  = t >> 1;
        int hk = (t & 1)*64;
        int combo = cBase + r;
        if (combo >= NCOMB) combo = NCOMB - 1;
        int rr = combo / NUM_TS;
        int tt = combo - rr*NUM_TS;
        const float4* rv4 = (const float4*)(relP + (size_t)rr*D + hk);
        const float4* tv4 = (const float4*)(timP + (size_t)tt*D + hk);
        const float4* bv4 = (const float4*)(b_rt + hk);
        unsigned short* dst = Hs + r*XPAD + hk;
        #pragma unroll
        for (int g = 0; g < 16; ++g) {
            float4 rv = rv4[g], tv = tv4[g], bv = bv4[g];
            float v0 = lrelu(rv.x+tv.x+bv.x), v1 = lrelu(rv.y+tv.y+bv.y);
            float v2 = lrelu(rv.z+tv.z+bv.z), v3 = lrelu(rv.w+tv.w+bv.w);
            *(uint2*)(dst + g*4) = make_uint2(pk2(v0,v1), pk2(v2,v3));
        }
    }
    __syncthreads();

    int w = t >> 6, l = t & 63;
    int li = l & 15, q = l >> 4;
    int mb = (w & 1)*4;        // m-tile base: cols (mb+mi)*16
    int nb = (w >> 1)*64;      // combo base within block

    f32x4 acc[4][4];
    #pragma unroll
    for (int mi = 0; mi < 4; ++mi)
        #pragma unroll
        for (int ni = 0; ni < 4; ++ni) acc[mi][ni] = (f32x4){0.f,0.f,0.f,0.f};

    #pragma unroll 1
    for (int s = 0; s < 4; ++s) {
        short8 af[4], bf[4];
        #pragma unroll
        for (int mi = 0; mi < 4; ++mi)
            af[mi] = *(const short8*)(Wpk2 + ((size_t)((mb+mi)*4 + s)*64 + l)*8);
        #pragma unroll
        for (int ni = 0; ni < 4; ++ni)
            bf[ni] = *(const short8*)(Hs + (nb + ni*16 + li)*XPAD + s*32 + q*8);
        #pragma unroll
        for (int mi = 0; mi < 4; ++mi)
            #pragma unroll
            for (int ni = 0; ni < 4; ++ni)
                acc[mi][ni] = __builtin_amdgcn_mfma_f32_16x16x32_bf16(
                                  af[mi], bf[ni], acc[mi][ni], 0, 0, 0);
    }
    #pragma unroll
    for (int ni = 0; ni < 4; ++ni) {
        int combo = cBase + nb + ni*16 + li;
        if (combo >= NCOMB) continue;
        #pragma unroll
        for (int mi = 0; mi < 4; ++mi) {
            int col = (mb + mi)*16 + q*4;
            *(uint2*)(T2bf + (size_t)combo*D + col) =
                make_uint2(pk2(acc[mi][ni][0], acc[mi][ni][1]),
                           pk2(acc[mi][ni][2], acc[mi][ni][3]));
        }
    }
}

__global__ __launch_bounds__(256, 3) void k_mm(
        const float* __restrict__ x, const unsigned short* __restrict__ Wpk13,
        unsigned short* __restrict__ xW13bf, int n_nodes,
        const float* __restrict__ relP, const float* __restrict__ timP,
        const float* __restrict__ b_rt, const unsigned short* __restrict__ Wpk2,
        unsigned short* __restrict__ T2bf, int nxw)
{
    __shared__ __align__(16) unsigned short Hs[128*XPAD];  // 34.8 KB (union)
    int b = blockIdx.x;
    if (b < nxw) {
        xw_body(b, x, Wpk13, xW13bf, n_nodes, Hs);
    } else {
        t2_body(b - nxw, relP, timP, b_rt, Wpk2, T2bf, Hs);
    }
}

// ---------------------------------------------------------------------------
// Launch 4 — k_agg: one wave per dst node, 2 cols per lane.
// Batch-16 fully-unrolled predicated pipeline: issue up to 16 independent
// broadcast index loads, then up to 32 independent row-gathers, then consume.
// No serial remainder path (was: x4 unroll + dependent-chain remainder loop).
// j < m is wave-uniform -> guards compile to exec-mask/scalar-branch skips.
// One batch covers P(deg<=16) ~ 99.6% of nodes (Poisson mean 8).
// ---------------------------------------------------------------------------
__global__ __launch_bounds__(256) void k_agg(
        const int* __restrict__ deg, const int2* __restrict__ ebuf,
        const unsigned short* __restrict__ xW13bf,
        const unsigned short* __restrict__ T2bf,
        const float* __restrict__ b_fc,
        float* __restrict__ out, int n_nodes)
{
    int node = blockIdx.x*4 + (threadIdx.x >> 6);
    int lane = threadIdx.x & 63;
    if (node >= n_nodes) return;
    int dg  = deg[node];
    int cnt = dg < MAXDEG ? dg : MAXDEG;
    const int2* eb = ebuf + (size_t)node*MAXDEG;

    float2 bb = *(const float2*)&b_fc[2*lane];
    unsigned xw3 = *(const unsigned*)&xW13bf[(size_t)node*256 + 128 + 2*lane];
    float base0 = bf_lo(xw3) + bb.x;
    float base1 = bf_hi(xw3) + bb.y;

    float s0 = 0.f, s1 = 0.f;   // even-j accumulators
    float r0 = 0.f, r1 = 0.f;   // odd-j accumulators (shorten fp add chain)

    for (int e = 0; e < cnt; e += 16) {
        int m = cnt - e;                       // wave-uniform residual count
        int2 ed[16]; unsigned sv[16], tv[16];
        #pragma unroll
        for (int j = 0; j < 16; ++j)
            if (j < m) ed[j] = eb[e + j];      // independent broadcast loads
        #pragma unroll
        for (int j = 0; j < 16; ++j)
            if (j < m) {
                sv[j] = *(const unsigned*)&xW13bf[(size_t)ed[j].x*256 + 2*lane];
                tv[j] = *(const unsigned*)&T2bf  [(size_t)ed[j].y*D   + 2*lane];
            }
        #pragma unroll
        for (int j = 0; j < 16; ++j)
            if (j < m) {
                if (j & 1) {
                    r0 += lrelu(bf_lo(sv[j]) + bf_lo(tv[j]) + base0);
                    r1 += lrelu(bf_hi(sv[j]) + bf_hi(tv[j]) + base1);
                } else {
                    s0 += lrelu(bf_lo(sv[j]) + bf_lo(tv[j]) + base0);
                    s1 += lrelu(bf_hi(sv[j]) + bf_hi(tv[j]) + base1);
                }
            }
    }
    float inv = 1.f / fmaxf((float)dg, 1.f);
    *(float2*)&out[(size_t)node*D + 2*lane] =
        make_float2((s0 + r0)*inv, (s1 + r1)*inv);
}

// ---------------------------------------------------------------------------
extern "C" void kernel_launch(void* const* d_in, const int* in_sizes, int n_in,
                              void* d_out, int out_size, void* d_ws, size_t ws_size,
                              hipStream_t stream)
{
    const float* x          = (const float*)d_in[0];
    const float* rel_table  = (const float*)d_in[1];
    const float* time_table = (const float*)d_in[2];
    const float* W_rt       = (const float*)d_in[3];
    const float* b_rt       = (const float*)d_in[4];
    const float* W_fc       = (const float*)d_in[5];
    const float* b_fc       = (const float*)d_in[6];
    const int*   edges      = (const int*)d_in[7];

    int n_nodes = in_sizes[0] / D;   // 50000
    int n_edges = in_sizes[7] / 4;   // 400000
    int nblkE   = (n_edges + 255) / 256;   // 1563
    int nxw     = (n_nodes + 63) / 64;     // 782
    int nt2     = (NCOMB + 127) / 128;     // 656

    char* ws = (char*)d_ws;
    size_t off = 0;
    auto alloc = [&](size_t bytes) -> void* {
        void* p = ws + off; off += (bytes + 255) & ~(size_t)255; return p;
    };
    unsigned short* xW13bf = (unsigned short*)alloc((size_t)n_nodes * 256 * 2); // 25.6 MB
    unsigned short* T2bf   = (unsigned short*)alloc((size_t)NCOMB * D * 2);     // 21.5 MB
    unsigned short* Wpk13  = (unsigned short*)alloc((size_t)16*4*64*8 * 2);     // 64 KB
    unsigned short* Wpk2   = (unsigned short*)alloc((size_t)8*4*64*8 * 2);      // 32 KB
    float* relP   = (float*)alloc((size_t)NUM_REL * D * sizeof(float));
    float* timP   = (float*)alloc((size_t)NUM_TS * D * sizeof(float));
    int*   deg    = (int*)alloc((size_t)n_nodes * sizeof(int));
    int2*  ebuf   = (int2*)alloc((size_t)n_nodes * MAXDEG * sizeof(int2));      // 25.6 MB
    if (off > ws_size)
        fprintf(stderr, "kernel_launch: workspace too small: need %zu, have %zu\n", off, ws_size);

    hipMemsetAsync(deg, 0, (size_t)n_nodes * sizeof(int), stream);

    k_prep<<<322 + nblkE, 256, 0, stream>>>(rel_table, time_table, W_rt, W_fc,
                                            edges, n_edges,
                                            relP, timP, Wpk13, Wpk2, deg, ebuf);
    k_mm  <<<nxw + nt2, 256, 0, stream>>>(x, Wpk13, xW13bf, n_nodes,
                                          relP, timP, b_rt, Wpk2, T2bf, nxw);
    k_agg <<<(n_nodes + 3)/4, 256, 0, stream>>>(deg, ebuf, xW13bf, T2bf,
                                                b_fc, (float*)d_out, n_nodes);
}

// Round 2
// 179.677 us; speedup vs baseline: 1.1246x; 1.1246x over previous
//
#include <hip/hip_runtime.h>
#include <cstdio>

#define HID 64
#define D 128            // 2*HID
#define NUM_REL 230
#define NUM_TS 365
#define NCOMB (NUM_REL*NUM_TS)   // 83950
#define SLOPE 0.2f
#define XPAD 136         // LDS row stride in bf16 (272 B -> 2-way bank alias, free)
#define MAXDEG 64        // Poisson(8) max degree ~25; P(deg>=64) < 1e-40

typedef __attribute__((ext_vector_type(8))) short short8;
typedef __attribute__((ext_vector_type(4))) float f32x4;

__device__ __forceinline__ float lrelu(float v){ return v >= 0.f ? v : SLOPE*v; }

// bf16 helpers
__device__ __forceinline__ unsigned bf_rne(float f){
    unsigned u = __float_as_uint(f);
    return (u + 0x7fffu + ((u >> 16) & 1u)) >> 16;
}
__device__ __forceinline__ unsigned pk2(float a, float b){
    return bf_rne(a) | (bf_rne(b) << 16);
}
__device__ __forceinline__ float bf_lo(unsigned u){ return __uint_as_float(u << 16); }
__device__ __forceinline__ float bf_hi(unsigned u){ return __uint_as_float(u & 0xffff0000u); }

// ---------------------------------------------------------------------------
// Launch 2 — k_prep: parts (relP/timP) + W-pack + edge bucket-scatter.
// blocks [0,298)        : relP/timP rows (2 rows per block)
// blocks [298,322)      : pack W13^T / W2^T into MFMA A-frag order (bf16)
// blocks [322,322+NE256): slot = atomicAdd(deg[dst]); ebuf[dst*MAXDEG+slot]
// ---------------------------------------------------------------------------
__global__ __launch_bounds__(256) void k_prep(
        const float* __restrict__ rel_table, const float* __restrict__ time_table,
        const float* __restrict__ W_rt, const float* __restrict__ W_fc,
        const int* __restrict__ edges, int n_edges,
        float* __restrict__ relP, float* __restrict__ timP,
        unsigned short* __restrict__ Wpk13, unsigned short* __restrict__ Wpk2,
        int* __restrict__ deg, int2* __restrict__ ebuf)
{
    int b = blockIdx.x;
    if (b < 298) {
        int row = b*2 + (threadIdx.x >> 7);
        int j   = threadIdx.x & 127;
        if (row >= NUM_REL + NUM_TS) return;
        const float* tbl; const float* Wb; float* out;
        if (row < NUM_REL) { tbl = rel_table + row*HID;            Wb = W_rt;          out = relP + row*D; }
        else               { tbl = time_table + (row-NUM_REL)*HID; Wb = W_rt + HID*D;  out = timP + (row-NUM_REL)*D; }
        float acc = 0.f;
        #pragma unroll
        for (int k = 0; k < HID; ++k) acc += tbl[k] * Wb[k*D + j];
        out[j] = acc;
    } else if (b < 322) {
        int id = (b - 298)*256 + threadIdx.x;   // 0..6143
        if (id < 4096) {                 // W13 frags
            int mt = id >> 8;            // 0..15
            int s  = (id >> 6) & 3;
            int l  = id & 63;
            int m  = mt*16 + (l & 15);   // output col 0..255
            int kb = s*32 + (l >> 4)*8;
            unsigned short* dst = Wpk13 + ((size_t)(mt*4 + s)*64 + l)*8;
            #pragma unroll
            for (int j = 0; j < 8; ++j) {
                int k = kb + j;
                float v = (m < D) ? W_fc[(size_t)k*D + m]
                                  : W_fc[(size_t)(256 + k)*D + (m - D)];
                dst[j] = (unsigned short)bf_rne(v);
            }
        } else {                         // W2 frags
            int id2 = id - 4096;
            int mt = id2 >> 8;           // 0..7
            int s  = (id2 >> 6) & 3;
            int l  = id2 & 63;
            int m  = mt*16 + (l & 15);
            int kb = s*32 + (l >> 4)*8;
            unsigned short* dst = Wpk2 + ((size_t)(mt*4 + s)*64 + l)*8;
            #pragma unroll
            for (int j = 0; j < 8; ++j) {
                int k = kb + j;
                dst[j] = (unsigned short)bf_rne(W_fc[(size_t)(D + k)*D + m]);
            }
        }
    } else {
        int e = (b - 322)*256 + threadIdx.x;
        if (e < n_edges) {
            int4 ed = ((const int4*)edges)[e];
            int slot = atomicAdd(&deg[ed.y], 1);
            if (slot < MAXDEG)   // safety clamp; statistically never taken
                ebuf[(size_t)ed.y*MAXDEG + slot] = make_int2(ed.x, ed.z*NUM_TS + ed.w);
        }
    }
}

// ---------------------------------------------------------------------------
// Launch 3 — k_mm: xw MFMA blocks + t2 MFMA blocks, one grid.
// ---------------------------------------------------------------------------
__device__ __forceinline__ void xw_body(
        int xb, const float* __restrict__ x,
        const unsigned short* __restrict__ Wpk13,
        unsigned short* __restrict__ xW13bf, int n_nodes,
        unsigned short* Xs /* 64*XPAD */)
{
    int t = threadIdx.x;
    int nodeBase = xb*64;
    {   // stage X tile (fp32 -> bf16), 4 threads per node row
        int row = t >> 2;
        int k0  = (t & 3)*32;
        int node = nodeBase + row;
        unsigned short* dst = Xs + row*XPAD + k0;
        if (node < n_nodes) {
            const float4* src = (const float4*)(x + (size_t)node*D + k0);
            #pragma unroll
            for (int g = 0; g < 8; ++g) {
                float4 v = src[g];
                *(uint2*)(dst + g*4) = make_uint2(pk2(v.x, v.y), pk2(v.z, v.w));
            }
        } else {
            #pragma unroll
            for (int g = 0; g < 8; ++g)
                *(uint2*)(dst + g*4) = make_uint2(0u, 0u);
        }
    }
    __syncthreads();

    int w = t >> 6, l = t & 63;
    int li = l & 15, q = l >> 4;

    f32x4 acc[4][4];
    #pragma unroll
    for (int mi = 0; mi < 4; ++mi)
        #pragma unroll
        for (int ni = 0; ni < 4; ++ni) acc[mi][ni] = (f32x4){0.f,0.f,0.f,0.f};

    #pragma unroll 1
    for (int s = 0; s < 4; ++s) {
        short8 af[4], bf[4];
        #pragma unroll
        for (int mi = 0; mi < 4; ++mi) {
            int mt = w*4 + mi;
            af[mi] = *(const short8*)(Wpk13 + ((size_t)(mt*4 + s)*64 + l)*8);
        }
        #pragma unroll
        for (int ni = 0; ni < 4; ++ni)
            bf[ni] = *(const short8*)(Xs + (ni*16 + li)*XPAD + s*32 + q*8);
        #pragma unroll
        for (int mi = 0; mi < 4; ++mi)
            #pragma unroll
            for (int ni = 0; ni < 4; ++ni)
                acc[mi][ni] = __builtin_amdgcn_mfma_f32_16x16x32_bf16(
                                  af[mi], bf[ni], acc[mi][ni], 0, 0, 0);
    }
    #pragma unroll
    for (int ni = 0; ni < 4; ++ni) {
        int node = nodeBase + ni*16 + li;
        if (node >= n_nodes) continue;
        #pragma unroll
        for (int mi = 0; mi < 4; ++mi) {
            int col = w*64 + mi*16 + q*4;
            *(uint2*)(xW13bf + (size_t)node*256 + col) =
                make_uint2(pk2(acc[mi][ni][0], acc[mi][ni][1]),
                           pk2(acc[mi][ni][2], acc[mi][ni][3]));
        }
    }
}

__device__ __forceinline__ void t2_body(
        int tb, const float* __restrict__ relP, const float* __restrict__ timP,
        const float* __restrict__ b_rt, const unsigned short* __restrict__ Wpk2,
        unsigned short* __restrict__ T2bf,
        unsigned short* Hs /* 128*XPAD */)
{
    int t = threadIdx.x;
    int cBase = tb*128;
    {   // stage H tile: compute lrelu(relP+timP+b) -> bf16, 2 threads per row
        int r  = t >> 1;
        int hk = (t & 1)*64;
        int combo = cBase + r;
        if (combo >= NCOMB) combo = NCOMB - 1;
        int rr = combo / NUM_TS;
        int tt = combo - rr*NUM_TS;
        const float4* rv4 = (const float4*)(relP + (size_t)rr*D + hk);
        const float4* tv4 = (const float4*)(timP + (size_t)tt*D + hk);
        const float4* bv4 = (const float4*)(b_rt + hk);
        unsigned short* dst = Hs + r*XPAD + hk;
        #pragma unroll
        for (int g = 0; g < 16; ++g) {
            float4 rv = rv4[g], tv = tv4[g], bv = bv4[g];
            float v0 = lrelu(rv.x+tv.x+bv.x), v1 = lrelu(rv.y+tv.y+bv.y);
            float v2 = lrelu(rv.z+tv.z+bv.z), v3 = lrelu(rv.w+tv.w+bv.w);
            *(uint2*)(dst + g*4) = make_uint2(pk2(v0,v1), pk2(v2,v3));
        }
    }
    __syncthreads();

    int w = t >> 6, l = t & 63;
    int li = l & 15, q = l >> 4;
    int mb = (w & 1)*4;        // m-tile base: cols (mb+mi)*16
    int nb = (w >> 1)*64;      // combo base within block

    f32x4 acc[4][4];
    #pragma unroll
    for (int mi = 0; mi < 4; ++mi)
        #pragma unroll
        for (int ni = 0; ni < 4; ++ni) acc[mi][ni] = (f32x4){0.f,0.f,0.f,0.f};

    #pragma unroll 1
    for (int s = 0; s < 4; ++s) {
        short8 af[4], bf[4];
        #pragma unroll
        for (int mi = 0; mi < 4; ++mi)
            af[mi] = *(const short8*)(Wpk2 + ((size_t)((mb+mi)*4 + s)*64 + l)*8);
        #pragma unroll
        for (int ni = 0; ni < 4; ++ni)
            bf[ni] = *(const short8*)(Hs + (nb + ni*16 + li)*XPAD + s*32 + q*8);
        #pragma unroll
        for (int mi = 0; mi < 4; ++mi)
            #pragma unroll
            for (int ni = 0; ni < 4; ++ni)
                acc[mi][ni] = __builtin_amdgcn_mfma_f32_16x16x32_bf16(
                                  af[mi], bf[ni], acc[mi][ni], 0, 0, 0);
    }
    #pragma unroll
    for (int ni = 0; ni < 4; ++ni) {
        int combo = cBase + nb + ni*16 + li;
        if (combo >= NCOMB) continue;
        #pragma unroll
        for (int mi = 0; mi < 4; ++mi) {
            int col = (mb + mi)*16 + q*4;
            *(uint2*)(T2bf + (size_t)combo*D + col) =
                make_uint2(pk2(acc[mi][ni][0], acc[mi][ni][1]),
                           pk2(acc[mi][ni][2], acc[mi][ni][3]));
        }
    }
}

__global__ __launch_bounds__(256, 3) void k_mm(
        const float* __restrict__ x, const unsigned short* __restrict__ Wpk13,
        unsigned short* __restrict__ xW13bf, int n_nodes,
        const float* __restrict__ relP, const float* __restrict__ timP,
        const float* __restrict__ b_rt, const unsigned short* __restrict__ Wpk2,
        unsigned short* __restrict__ T2bf, int nxw)
{
    __shared__ __align__(16) unsigned short Hs[128*XPAD];  // 34.8 KB (union)
    int b = blockIdx.x;
    if (b < nxw) {
        xw_body(b, x, Wpk13, xW13bf, n_nodes, Hs);
    } else {
        t2_body(b - nxw, relP, timP, b_rt, Wpk2, T2bf, Hs);
    }
}

// ---------------------------------------------------------------------------
// Launch 4 — k_agg: 4 nodes per wave, 16 lanes per node, uint4 (16B) gathers.
// Each gather instruction serves 4 independent edge streams (4 rows x 256B =
// 1KB/instr); x4 edge unroll -> 8KB outstanding per wave (4x MLP vs 1-node
// wave). Straight-line named-variable batching — NO guarded loads (round-1
// lesson: hipcc merges guarded unrolled load loops into serial chains).
// Per-group remainder handled by clamped indices + cndmask-masked accumulate:
// loads always execute (clamp keeps them in-bounds and L2-hot).
// ---------------------------------------------------------------------------
__global__ __launch_bounds__(256) void k_agg(
        const int* __restrict__ deg, const int2* __restrict__ ebuf,
        const unsigned short* __restrict__ xW13bf,
        const unsigned short* __restrict__ T2bf,
        const float* __restrict__ b_fc,
        float* __restrict__ out, int n_nodes)
{
    int t    = threadIdx.x;
    int lane = t & 63;
    int g    = lane >> 4;             // node group within wave (0..3)
    int sub  = lane & 15;             // lane within group; covers cols sub*8..+7
    int node = blockIdx.x*16 + (t >> 6)*4 + g;
    bool valid = node < n_nodes;
    int nodeC  = valid ? node : n_nodes - 1;

    int dg  = deg[nodeC];
    int cnt = valid ? (dg < MAXDEG ? dg : MAXDEG) : 0;
    int cm1 = cnt > 0 ? cnt - 1 : 0;
    const int2* eb = ebuf + (size_t)nodeC * MAXDEG;

    // wave-max trip count (cnt is uniform within each 16-lane group)
    int cmax = cnt;
    cmax = max(cmax, __shfl_xor(cmax, 16));
    cmax = max(cmax, __shfl_xor(cmax, 32));

    // base = xW3[node] + b_fc for this lane's 8 cols
    float base[8];
    {
        uint4  w3  = *(const uint4*)&xW13bf[(size_t)nodeC*256 + 128 + sub*8];
        float4 blo = *(const float4*)&b_fc[sub*8];
        float4 bhi = *(const float4*)&b_fc[sub*8 + 4];
        base[0] = bf_lo(w3.x) + blo.x; base[1] = bf_hi(w3.x) + blo.y;
        base[2] = bf_lo(w3.y) + blo.z; base[3] = bf_hi(w3.y) + blo.w;
        base[4] = bf_lo(w3.z) + bhi.x; base[5] = bf_hi(w3.z) + bhi.y;
        base[6] = bf_lo(w3.w) + bhi.z; base[7] = bf_hi(w3.w) + bhi.w;
    }

    float acc[8];
    #pragma unroll
    for (int k = 0; k < 8; ++k) acc[k] = 0.f;

    const unsigned sMax = (unsigned)(n_nodes - 1);
    const unsigned cMax = (unsigned)(NCOMB - 1);

    for (int e = 0; e < cmax; e += 4) {
        // --- batch 1: index loads (independent, clamped in-bounds) ---
        int2 e0 = eb[min(e + 0, cm1)];
        int2 e1 = eb[min(e + 1, cm1)];
        int2 e2 = eb[min(e + 2, cm1)];
        int2 e3 = eb[min(e + 3, cm1)];
        // --- clamp gather targets (garbage-safe for masked slots) ---
        unsigned s0 = min((unsigned)e0.x, sMax), c0 = min((unsigned)e0.y, cMax);
        unsigned s1 = min((unsigned)e1.x, sMax), c1 = min((unsigned)e1.y, cMax);
        unsigned s2 = min((unsigned)e2.x, sMax), c2 = min((unsigned)e2.y, cMax);
        unsigned s3 = min((unsigned)e3.x, sMax), c3 = min((unsigned)e3.y, cMax);
        // --- batch 2: 8 independent 16B gathers ---
        uint4 S0 = *(const uint4*)&xW13bf[(size_t)s0*256 + sub*8];
        uint4 T0 = *(const uint4*)&T2bf  [(size_t)c0*D   + sub*8];
        uint4 S1 = *(const uint4*)&xW13bf[(size_t)s1*256 + sub*8];
        uint4 T1 = *(const uint4*)&T2bf  [(size_t)c1*D   + sub*8];
        uint4 S2 = *(const uint4*)&xW13bf[(size_t)s2*256 + sub*8];
        uint4 T2 = *(const uint4*)&T2bf  [(size_t)c2*D   + sub*8];
        uint4 S3 = *(const uint4*)&xW13bf[(size_t)s3*256 + sub*8];
        uint4 T3 = *(const uint4*)&T2bf  [(size_t)c3*D   + sub*8];
        // --- consume (cndmask-masked; no divergent control flow) ---
        bool m0 = (e + 0) < cnt, m1 = (e + 1) < cnt;
        bool m2 = (e + 2) < cnt, m3 = (e + 3) < cnt;
        #pragma unroll
        for (int w = 0; w < 4; ++w) {
            unsigned Sw0 = (&S0.x)[w], Tw0 = (&T0.x)[w];
            unsigned Sw1 = (&S1.x)[w], Tw1 = (&T1.x)[w];
            unsigned Sw2 = (&S2.x)[w], Tw2 = (&T2.x)[w];
            unsigned Sw3 = (&S3.x)[w], Tw3 = (&T3.x)[w];
            float v0l = lrelu(bf_lo(Sw0) + bf_lo(Tw0) + base[2*w]);
            float v0h = lrelu(bf_hi(Sw0) + bf_hi(Tw0) + base[2*w+1]);
            float v1l = lrelu(bf_lo(Sw1) + bf_lo(Tw1) + base[2*w]);
            float v1h = lrelu(bf_hi(Sw1) + bf_hi(Tw1) + base[2*w+1]);
            float v2l = lrelu(bf_lo(Sw2) + bf_lo(Tw2) + base[2*w]);
            float v2h = lrelu(bf_hi(Sw2) + bf_hi(Tw2) + base[2*w+1]);
            float v3l = lrelu(bf_lo(Sw3) + bf_lo(Tw3) + base[2*w]);
            float v3h = lrelu(bf_hi(Sw3) + bf_hi(Tw3) + base[2*w+1]);
            float a01l = (m0 ? v0l : 0.f) + (m1 ? v1l : 0.f);
            float a23l = (m2 ? v2l : 0.f) + (m3 ? v3l : 0.f);
            float a01h = (m0 ? v0h : 0.f) + (m1 ? v1h : 0.f);
            float a23h = (m2 ? v2h : 0.f) + (m3 ? v3h : 0.f);
            acc[2*w]   += a01l + a23l;
            acc[2*w+1] += a01h + a23h;
        }
    }

    if (!valid) return;
    float inv = 1.f / fmaxf((float)dg, 1.f);
    float4 o0 = make_float4(acc[0]*inv, acc[1]*inv, acc[2]*inv, acc[3]*inv);
    float4 o1 = make_float4(acc[4]*inv, acc[5]*inv, acc[6]*inv, acc[7]*inv);
    *(float4*)&out[(size_t)node*D + sub*8]     = o0;
    *(float4*)&out[(size_t)node*D + sub*8 + 4] = o1;
}

// ---------------------------------------------------------------------------
extern "C" void kernel_launch(void* const* d_in, const int* in_sizes, int n_in,
                              void* d_out, int out_size, void* d_ws, size_t ws_size,
                              hipStream_t stream)
{
    const float* x          = (const float*)d_in[0];
    const float* rel_table  = (const float*)d_in[1];
    const float* time_table = (const float*)d_in[2];
    const float* W_rt       = (const float*)d_in[3];
    const float* b_rt       = (const float*)d_in[4];
    const float* W_fc       = (const float*)d_in[5];
    const float* b_fc       = (const float*)d_in[6];
    const int*   edges      = (const int*)d_in[7];

    int n_nodes = in_sizes[0] / D;   // 50000
    int n_edges = in_sizes[7] / 4;   // 400000
    int nblkE   = (n_edges + 255) / 256;   // 1563
    int nxw     = (n_nodes + 63) / 64;     // 782
    int nt2     = (NCOMB + 127) / 128;     // 656

    char* ws = (char*)d_ws;
    size_t off = 0;
    auto alloc = [&](size_t bytes) -> void* {
        void* p = ws + off; off += (bytes + 255) & ~(size_t)255; return p;
    };
    unsigned short* xW13bf = (unsigned short*)alloc((size_t)n_nodes * 256 * 2); // 25.6 MB
    unsigned short* T2bf   = (unsigned short*)alloc((size_t)NCOMB * D * 2);     // 21.5 MB
    unsigned short* Wpk13  = (unsigned short*)alloc((size_t)16*4*64*8 * 2);     // 64 KB
    unsigned short* Wpk2   = (unsigned short*)alloc((size_t)8*4*64*8 * 2);      // 32 KB
    float* relP   = (float*)alloc((size_t)NUM_REL * D * sizeof(float));
    float* timP   = (float*)alloc((size_t)NUM_TS * D * sizeof(float));
    int*   deg    = (int*)alloc((size_t)n_nodes * sizeof(int));
    int2*  ebuf   = (int2*)alloc((size_t)n_nodes * MAXDEG * sizeof(int2));      // 25.6 MB
    if (off > ws_size)
        fprintf(stderr, "kernel_launch: workspace too small: need %zu, have %zu\n", off, ws_size);

    hipMemsetAsync(deg, 0, (size_t)n_nodes * sizeof(int), stream);

    k_prep<<<322 + nblkE, 256, 0, stream>>>(rel_table, time_table, W_rt, W_fc,
                                            edges, n_edges,
                                            relP, timP, Wpk13, Wpk2, deg, ebuf);
    k_mm  <<<nxw + nt2, 256, 0, stream>>>(x, Wpk13, xW13bf, n_nodes,
                                          relP, timP, b_rt, Wpk2, T2bf, nxw);
    k_agg <<<(n_nodes + 15)/16, 256, 0, stream>>>(deg, ebuf, xW13bf, T2bf,
                                                  b_fc, (float*)d_out, n_nodes);
}

// Round 4
// 177.599 us; speedup vs baseline: 1.1377x; 1.0117x over previous
//
#include <hip/hip_runtime.h>
#include <cstdio>

#define HID 64
#define D 128            // 2*HID
#define NUM_REL 230
#define NUM_TS 365
#define NCOMB (NUM_REL*NUM_TS)   // 83950
#define SLOPE 0.2f
#define XPAD 136         // LDS row stride in bf16 (272 B -> 2-way bank alias, free)
#define MAXDEG 64        // Poisson(8) max degree ~25; P(deg>=64) < 1e-40

typedef __attribute__((ext_vector_type(8))) short short8;
typedef __attribute__((ext_vector_type(4))) float f32x4;

__device__ __forceinline__ float lrelu(float v){ return v >= 0.f ? v : SLOPE*v; }

// bf16 helpers
__device__ __forceinline__ unsigned bf_rne(float f){
    unsigned u = __float_as_uint(f);
    return (u + 0x7fffu + ((u >> 16) & 1u)) >> 16;
}
__device__ __forceinline__ unsigned pk2(float a, float b){
    return bf_rne(a) | (bf_rne(b) << 16);
}
__device__ __forceinline__ float bf_lo(unsigned u){ return __uint_as_float(u << 16); }
__device__ __forceinline__ float bf_hi(unsigned u){ return __uint_as_float(u & 0xffff0000u); }

// ---------------------------------------------------------------------------
// Launch 2 — k_prep: parts (relP/timP) + W-pack ONLY.
// blocks [0,298)   : relP/timP rows (2 rows per block)
// blocks [298,322) : pack W13^T / W2^T into MFMA A-frag order (bf16)
// deg zeroing stays in hipMemsetAsync (proven blit->atomics pattern);
// edge scatter moved to k_mm's grid (scatter->k_agg crosses a dispatch
// boundary, same as rounds 0-2; no intra-k_mm data sharing).
// ---------------------------------------------------------------------------
__global__ __launch_bounds__(256) void k_prep(
        const float* __restrict__ rel_table, const float* __restrict__ time_table,
        const float* __restrict__ W_rt, const float* __restrict__ W_fc,
        float* __restrict__ relP, float* __restrict__ timP,
        unsigned short* __restrict__ Wpk13, unsigned short* __restrict__ Wpk2)
{
    int b = blockIdx.x;
    if (b < 298) {
        int row = b*2 + (threadIdx.x >> 7);
        int j   = threadIdx.x & 127;
        if (row >= NUM_REL + NUM_TS) return;
        const float* tbl; const float* Wb; float* out;
        if (row < NUM_REL) { tbl = rel_table + row*HID;            Wb = W_rt;          out = relP + row*D; }
        else               { tbl = time_table + (row-NUM_REL)*HID; Wb = W_rt + HID*D;  out = timP + (row-NUM_REL)*D; }
        float acc = 0.f;
        #pragma unroll
        for (int k = 0; k < HID; ++k) acc += tbl[k] * Wb[k*D + j];
        out[j] = acc;
    } else {
        int id = (b - 298)*256 + threadIdx.x;   // 0..6143
        if (id < 4096) {                 // W13 frags
            int mt = id >> 8;            // 0..15
            int s  = (id >> 6) & 3;
            int l  = id & 63;
            int m  = mt*16 + (l & 15);   // output col 0..255
            int kb = s*32 + (l >> 4)*8;
            unsigned short* dst = Wpk13 + ((size_t)(mt*4 + s)*64 + l)*8;
            #pragma unroll
            for (int j = 0; j < 8; ++j) {
                int k = kb + j;
                float v = (m < D) ? W_fc[(size_t)k*D + m]
                                  : W_fc[(size_t)(256 + k)*D + (m - D)];
                dst[j] = (unsigned short)bf_rne(v);
            }
        } else {                         // W2 frags
            int id2 = id - 4096;
            int mt = id2 >> 8;           // 0..7
            int s  = (id2 >> 6) & 3;
            int l  = id2 & 63;
            int m  = mt*16 + (l & 15);
            int kb = s*32 + (l >> 4)*8;
            unsigned short* dst = Wpk2 + ((size_t)(mt*4 + s)*64 + l)*8;
            #pragma unroll
            for (int j = 0; j < 8; ++j) {
                int k = kb + j;
                dst[j] = (unsigned short)bf_rne(W_fc[(size_t)(D + k)*D + m]);
            }
        }
    }
}

// ---------------------------------------------------------------------------
// Launch 3 — k_mm: edge-scatter blocks FIRST (latency-bound, overlap with
// MFMA), then xw MFMA blocks, then t2 MFMA blocks — one grid.
// ---------------------------------------------------------------------------
__device__ __forceinline__ void xw_body(
        int xb, const float* __restrict__ x,
        const unsigned short* __restrict__ Wpk13,
        unsigned short* __restrict__ xW13bf, int n_nodes,
        unsigned short* Xs /* 64*XPAD */)
{
    int t = threadIdx.x;
    int nodeBase = xb*64;
    {   // stage X tile (fp32 -> bf16), 4 threads per node row
        int row = t >> 2;
        int k0  = (t & 3)*32;
        int node = nodeBase + row;
        unsigned short* dst = Xs + row*XPAD + k0;
        if (node < n_nodes) {
            const float4* src = (const float4*)(x + (size_t)node*D + k0);
            #pragma unroll
            for (int g = 0; g < 8; ++g) {
                float4 v = src[g];
                *(uint2*)(dst + g*4) = make_uint2(pk2(v.x, v.y), pk2(v.z, v.w));
            }
        } else {
            #pragma unroll
            for (int g = 0; g < 8; ++g)
                *(uint2*)(dst + g*4) = make_uint2(0u, 0u);
        }
    }
    __syncthreads();

    int w = t >> 6, l = t & 63;
    int li = l & 15, q = l >> 4;

    f32x4 acc[4][4];
    #pragma unroll
    for (int mi = 0; mi < 4; ++mi)
        #pragma unroll
        for (int ni = 0; ni < 4; ++ni) acc[mi][ni] = (f32x4){0.f,0.f,0.f,0.f};

    #pragma unroll 1
    for (int s = 0; s < 4; ++s) {
        short8 af[4], bf[4];
        #pragma unroll
        for (int mi = 0; mi < 4; ++mi) {
            int mt = w*4 + mi;
            af[mi] = *(const short8*)(Wpk13 + ((size_t)(mt*4 + s)*64 + l)*8);
        }
        #pragma unroll
        for (int ni = 0; ni < 4; ++ni)
            bf[ni] = *(const short8*)(Xs + (ni*16 + li)*XPAD + s*32 + q*8);
        #pragma unroll
        for (int mi = 0; mi < 4; ++mi)
            #pragma unroll
            for (int ni = 0; ni < 4; ++ni)
                acc[mi][ni] = __builtin_amdgcn_mfma_f32_16x16x32_bf16(
                                  af[mi], bf[ni], acc[mi][ni], 0, 0, 0);
    }
    #pragma unroll
    for (int ni = 0; ni < 4; ++ni) {
        int node = nodeBase + ni*16 + li;
        if (node >= n_nodes) continue;
        #pragma unroll
        for (int mi = 0; mi < 4; ++mi) {
            int col = w*64 + mi*16 + q*4;
            *(uint2*)(xW13bf + (size_t)node*256 + col) =
                make_uint2(pk2(acc[mi][ni][0], acc[mi][ni][1]),
                           pk2(acc[mi][ni][2], acc[mi][ni][3]));
        }
    }
}

__device__ __forceinline__ void t2_body(
        int tb, const float* __restrict__ relP, const float* __restrict__ timP,
        const float* __restrict__ b_rt, const unsigned short* __restrict__ Wpk2,
        unsigned short* __restrict__ T2bf,
        unsigned short* Hs /* 128*XPAD */)
{
    int t = threadIdx.x;
    int cBase = tb*128;
    {   // stage H tile: compute lrelu(relP+timP+b) -> bf16, 2 threads per row
        int r  = t >> 1;
        int hk = (t & 1)*64;
        int combo = cBase + r;
        if (combo >= NCOMB) combo = NCOMB - 1;
        int rr = combo / NUM_TS;
        int tt = combo - rr*NUM_TS;
        const float4* rv4 = (const float4*)(relP + (size_t)rr*D + hk);
        const float4* tv4 = (const float4*)(timP + (size_t)tt*D + hk);
        const float4* bv4 = (const float4*)(b_rt + hk);
        unsigned short* dst = Hs + r*XPAD + hk;
        #pragma unroll
        for (int g = 0; g < 16; ++g) {
            float4 rv = rv4[g], tv = tv4[g], bv = bv4[g];
            float v0 = lrelu(rv.x+tv.x+bv.x), v1 = lrelu(rv.y+tv.y+bv.y);
            float v2 = lrelu(rv.z+tv.z+bv.z), v3 = lrelu(rv.w+tv.w+bv.w);
            *(uint2*)(dst + g*4) = make_uint2(pk2(v0,v1), pk2(v2,v3));
        }
    }
    __syncthreads();

    int w = t >> 6, l = t & 63;
    int li = l & 15, q = l >> 4;
    int mb = (w & 1)*4;        // m-tile base: cols (mb+mi)*16
    int nb = (w >> 1)*64;      // combo base within block

    f32x4 acc[4][4];
    #pragma unroll
    for (int mi = 0; mi < 4; ++mi)
        #pragma unroll
        for (int ni = 0; ni < 4; ++ni) acc[mi][ni] = (f32x4){0.f,0.f,0.f,0.f};

    #pragma unroll 1
    for (int s = 0; s < 4; ++s) {
        short8 af[4], bf[4];
        #pragma unroll
        for (int mi = 0; mi < 4; ++mi)
            af[mi] = *(const short8*)(Wpk2 + ((size_t)((mb+mi)*4 + s)*64 + l)*8);
        #pragma unroll
        for (int ni = 0; ni < 4; ++ni)
            bf[ni] = *(const short8*)(Hs + (nb + ni*16 + li)*XPAD + s*32 + q*8);
        #pragma unroll
        for (int mi = 0; mi < 4; ++mi)
            #pragma unroll
            for (int ni = 0; ni < 4; ++ni)
                acc[mi][ni] = __builtin_amdgcn_mfma_f32_16x16x32_bf16(
                                  af[mi], bf[ni], acc[mi][ni], 0, 0, 0);
    }
    #pragma unroll
    for (int ni = 0; ni < 4; ++ni) {
        int combo = cBase + nb + ni*16 + li;
        if (combo >= NCOMB) continue;
        #pragma unroll
        for (int mi = 0; mi < 4; ++mi) {
            int col = (mb + mi)*16 + q*4;
            *(uint2*)(T2bf + (size_t)combo*D + col) =
                make_uint2(pk2(acc[mi][ni][0], acc[mi][ni][1]),
                           pk2(acc[mi][ni][2], acc[mi][ni][3]));
        }
    }
}

__global__ __launch_bounds__(256, 3) void k_mm(
        const float* __restrict__ x, const unsigned short* __restrict__ Wpk13,
        unsigned short* __restrict__ xW13bf, int n_nodes,
        const float* __restrict__ relP, const float* __restrict__ timP,
        const float* __restrict__ b_rt, const unsigned short* __restrict__ Wpk2,
        unsigned short* __restrict__ T2bf,
        const int* __restrict__ edges, int n_edges,
        int* __restrict__ deg, int2* __restrict__ ebuf,
        int nsc, int nxw)
{
    __shared__ __align__(16) unsigned short Hs[128*XPAD];  // 34.8 KB (union)
    int b = blockIdx.x;
    if (b < nsc) {
        // edge bucket-scatter: latency-bound; overlaps with MFMA blocks below.
        // deg was zeroed by hipMemsetAsync (blit) in the previous dispatch —
        // same blit->atomics pattern as the proven rounds-0-2 structure.
        int e = b*256 + threadIdx.x;
        if (e < n_edges) {
            int4 ed = ((const int4*)edges)[e];
            int slot = atomicAdd(&deg[ed.y], 1);
            if (slot < MAXDEG)   // safety clamp; statistically never taken
                ebuf[(size_t)ed.y*MAXDEG + slot] = make_int2(ed.x, ed.z*NUM_TS + ed.w);
        }
    } else if (b < nsc + nxw) {
        xw_body(b - nsc, x, Wpk13, xW13bf, n_nodes, Hs);
    } else {
        t2_body(b - nsc - nxw, relP, timP, b_rt, Wpk2, T2bf, Hs);
    }
}

// ---------------------------------------------------------------------------
// Launch 4 — k_agg: 4 nodes per wave, 16 lanes per node, uint4 (16B) gathers.
// (unchanged — measured at the random-gather path floor ~42 µs)
// ---------------------------------------------------------------------------
__global__ __launch_bounds__(256) void k_agg(
        const int* __restrict__ deg, const int2* __restrict__ ebuf,
        const unsigned short* __restrict__ xW13bf,
        const unsigned short* __restrict__ T2bf,
        const float* __restrict__ b_fc,
        float* __restrict__ out, int n_nodes)
{
    int t    = threadIdx.x;
    int lane = t & 63;
    int g    = lane >> 4;             // node group within wave (0..3)
    int sub  = lane & 15;             // lane within group; covers cols sub*8..+7
    int node = blockIdx.x*16 + (t >> 6)*4 + g;
    bool valid = node < n_nodes;
    int nodeC  = valid ? node : n_nodes - 1;

    int dg  = deg[nodeC];
    int cnt = valid ? (dg < MAXDEG ? dg : MAXDEG) : 0;
    int cm1 = cnt > 0 ? cnt - 1 : 0;
    const int2* eb = ebuf + (size_t)nodeC * MAXDEG;

    // wave-max trip count (cnt is uniform within each 16-lane group)
    int cmax = cnt;
    cmax = max(cmax, __shfl_xor(cmax, 16));
    cmax = max(cmax, __shfl_xor(cmax, 32));

    // base = xW3[node] + b_fc for this lane's 8 cols
    float base[8];
    {
        uint4  w3  = *(const uint4*)&xW13bf[(size_t)nodeC*256 + 128 + sub*8];
        float4 blo = *(const float4*)&b_fc[sub*8];
        float4 bhi = *(const float4*)&b_fc[sub*8 + 4];
        base[0] = bf_lo(w3.x) + blo.x; base[1] = bf_hi(w3.x) + blo.y;
        base[2] = bf_lo(w3.y) + blo.z; base[3] = bf_hi(w3.y) + blo.w;
        base[4] = bf_lo(w3.z) + bhi.x; base[5] = bf_hi(w3.z) + bhi.y;
        base[6] = bf_lo(w3.w) + bhi.z; base[7] = bf_hi(w3.w) + bhi.w;
    }

    float acc[8];
    #pragma unroll
    for (int k = 0; k < 8; ++k) acc[k] = 0.f;

    const unsigned sMax = (unsigned)(n_nodes - 1);
    const unsigned cMax = (unsigned)(NCOMB - 1);

    for (int e = 0; e < cmax; e += 4) {
        // --- batch 1: index loads (independent, clamped in-bounds) ---
        int2 e0 = eb[min(e + 0, cm1)];
        int2 e1 = eb[min(e + 1, cm1)];
        int2 e2 = eb[min(e + 2, cm1)];
        int2 e3 = eb[min(e + 3, cm1)];
        // --- clamp gather targets (garbage-safe for masked slots) ---
        unsigned s0 = min((unsigned)e0.x, sMax), c0 = min((unsigned)e0.y, cMax);
        unsigned s1 = min((unsigned)e1.x, sMax), c1 = min((unsigned)e1.y, cMax);
        unsigned s2 = min((unsigned)e2.x, sMax), c2 = min((unsigned)e2.y, cMax);
        unsigned s3 = min((unsigned)e3.x, sMax), c3 = min((unsigned)e3.y, cMax);
        // --- batch 2: 8 independent 16B gathers ---
        uint4 S0 = *(const uint4*)&xW13bf[(size_t)s0*256 + sub*8];
        uint4 T0 = *(const uint4*)&T2bf  [(size_t)c0*D   + sub*8];
        uint4 S1 = *(const uint4*)&xW13bf[(size_t)s1*256 + sub*8];
        uint4 T1 = *(const uint4*)&T2bf  [(size_t)c1*D   + sub*8];
        uint4 S2 = *(const uint4*)&xW13bf[(size_t)s2*256 + sub*8];
        uint4 T2 = *(const uint4*)&T2bf  [(size_t)c2*D   + sub*8];
        uint4 S3 = *(const uint4*)&xW13bf[(size_t)s3*256 + sub*8];
        uint4 T3 = *(const uint4*)&T2bf  [(size_t)c3*D   + sub*8];
        // --- consume (cndmask-masked; no divergent control flow) ---
        bool m0 = (e + 0) < cnt, m1 = (e + 1) < cnt;
        bool m2 = (e + 2) < cnt, m3 = (e + 3) < cnt;
        #pragma unroll
        for (int w = 0; w < 4; ++w) {
            unsigned Sw0 = (&S0.x)[w], Tw0 = (&T0.x)[w];
            unsigned Sw1 = (&S1.x)[w], Tw1 = (&T1.x)[w];
            unsigned Sw2 = (&S2.x)[w], Tw2 = (&T2.x)[w];
            unsigned Sw3 = (&S3.x)[w], Tw3 = (&T3.x)[w];
            float v0l = lrelu(bf_lo(Sw0) + bf_lo(Tw0) + base[2*w]);
            float v0h = lrelu(bf_hi(Sw0) + bf_hi(Tw0) + base[2*w+1]);
            float v1l = lrelu(bf_lo(Sw1) + bf_lo(Tw1) + base[2*w]);
            float v1h = lrelu(bf_hi(Sw1) + bf_hi(Tw1) + base[2*w+1]);
            float v2l = lrelu(bf_lo(Sw2) + bf_lo(Tw2) + base[2*w]);
            float v2h = lrelu(bf_hi(Sw2) + bf_hi(Tw2) + base[2*w+1]);
            float v3l = lrelu(bf_lo(Sw3) + bf_lo(Tw3) + base[2*w]);
            float v3h = lrelu(bf_hi(Sw3) + bf_hi(Tw3) + base[2*w+1]);
            float a01l = (m0 ? v0l : 0.f) + (m1 ? v1l : 0.f);
            float a23l = (m2 ? v2l : 0.f) + (m3 ? v3l : 0.f);
            float a01h = (m0 ? v0h : 0.f) + (m1 ? v1h : 0.f);
            float a23h = (m2 ? v2h : 0.f) + (m3 ? v3h : 0.f);
            acc[2*w]   += a01l + a23l;
            acc[2*w+1] += a01h + a23h;
        }
    }

    if (!valid) return;
    float inv = 1.f / fmaxf((float)dg, 1.f);
    float4 o0 = make_float4(acc[0]*inv, acc[1]*inv, acc[2]*inv, acc[3]*inv);
    float4 o1 = make_float4(acc[4]*inv, acc[5]*inv, acc[6]*inv, acc[7]*inv);
    *(float4*)&out[(size_t)node*D + sub*8]     = o0;
    *(float4*)&out[(size_t)node*D + sub*8 + 4] = o1;
}

// ---------------------------------------------------------------------------
extern "C" void kernel_launch(void* const* d_in, const int* in_sizes, int n_in,
                              void* d_out, int out_size, void* d_ws, size_t ws_size,
                              hipStream_t stream)
{
    const float* x          = (const float*)d_in[0];
    const float* rel_table  = (const float*)d_in[1];
    const float* time_table = (const float*)d_in[2];
    const float* W_rt       = (const float*)d_in[3];
    const float* b_rt       = (const float*)d_in[4];
    const float* W_fc       = (const float*)d_in[5];
    const float* b_fc       = (const float*)d_in[6];
    const int*   edges      = (const int*)d_in[7];

    int n_nodes = in_sizes[0] / D;   // 50000
    int n_edges = in_sizes[7] / 4;   // 400000
    int nblkE   = (n_edges + 255) / 256;   // 1563
    int nxw     = (n_nodes + 63) / 64;     // 782
    int nt2     = (NCOMB + 127) / 128;     // 656

    char* ws = (char*)d_ws;
    size_t off = 0;
    auto alloc = [&](size_t bytes) -> void* {
        void* p = ws + off; off += (bytes + 255) & ~(size_t)255; return p;
    };
    unsigned short* xW13bf = (unsigned short*)alloc((size_t)n_nodes * 256 * 2); // 25.6 MB
    unsigned short* T2bf   = (unsigned short*)alloc((size_t)NCOMB * D * 2);     // 21.5 MB
    unsigned short* Wpk13  = (unsigned short*)alloc((size_t)16*4*64*8 * 2);     // 64 KB
    unsigned short* Wpk2   = (unsigned short*)alloc((size_t)8*4*64*8 * 2);      // 32 KB
    float* relP   = (float*)alloc((size_t)NUM_REL * D * sizeof(float));
    float* timP   = (float*)alloc((size_t)NUM_TS * D * sizeof(float));
    int*   deg    = (int*)alloc((size_t)n_nodes * sizeof(int));
    int2*  ebuf   = (int2*)alloc((size_t)n_nodes * MAXDEG * sizeof(int2));      // 25.6 MB
    if (off > ws_size)
        fprintf(stderr, "kernel_launch: workspace too small: need %zu, have %zu\n", off, ws_size);

    hipMemsetAsync(deg, 0, (size_t)n_nodes * sizeof(int), stream);

    k_prep<<<322, 256, 0, stream>>>(rel_table, time_table, W_rt, W_fc,
                                    relP, timP, Wpk13, Wpk2);
    k_mm  <<<nblkE + nxw + nt2, 256, 0, stream>>>(x, Wpk13, xW13bf, n_nodes,
                                                  relP, timP, b_rt, Wpk2, T2bf,
                                                  edges, n_edges, deg, ebuf,
                                                  nblkE, nxw);
    k_agg <<<(n_nodes + 15)/16, 256, 0, stream>>>(deg, ebuf, xW13bf, T2bf,
                                                  b_fc, (float*)d_out, n_nodes);
}

// Round 5
// 169.915 us; speedup vs baseline: 1.1892x; 1.0452x over previous
//
#include <hip/hip_runtime.h>
#include <cstdio>

#define HID 64
#define D 128            // 2*HID
#define NUM_REL 230
#define NUM_TS 365
#define NCOMB (NUM_REL*NUM_TS)   // 83950
#define SLOPE 0.2f
#define XPAD 136         // LDS row stride in bf16 (272 B -> 2-way bank alias, free)
#define MAXDEG 64        // Poisson(8) max degree ~25; P(deg>=64) < 1e-40

typedef __attribute__((ext_vector_type(8))) short short8;
typedef __attribute__((ext_vector_type(4))) float f32x4;

__device__ __forceinline__ float lrelu(float v){ return v >= 0.f ? v : SLOPE*v; }

// bf16 helpers
__device__ __forceinline__ unsigned bf_rne(float f){
    unsigned u = __float_as_uint(f);
    return (u + 0x7fffu + ((u >> 16) & 1u)) >> 16;
}
__device__ __forceinline__ unsigned pk2(float a, float b){
    return bf_rne(a) | (bf_rne(b) << 16);
}
__device__ __forceinline__ float bf_lo(unsigned u){ return __uint_as_float(u << 16); }
__device__ __forceinline__ float bf_hi(unsigned u){ return __uint_as_float(u & 0xffff0000u); }

// ---------------------------------------------------------------------------
// Launch 2 — k_prep: parts (relP/timP) + W-pack ONLY.
// blocks [0,298)   : relP/timP rows (2 rows per block)
// blocks [298,322) : pack W13^T / W2^T into MFMA A-frag order (bf16)
// ---------------------------------------------------------------------------
__global__ __launch_bounds__(256) void k_prep(
        const float* __restrict__ rel_table, const float* __restrict__ time_table,
        const float* __restrict__ W_rt, const float* __restrict__ W_fc,
        float* __restrict__ relP, float* __restrict__ timP,
        unsigned short* __restrict__ Wpk13, unsigned short* __restrict__ Wpk2)
{
    int b = blockIdx.x;
    if (b < 298) {
        int row = b*2 + (threadIdx.x >> 7);
        int j   = threadIdx.x & 127;
        if (row >= NUM_REL + NUM_TS) return;
        const float* tbl; const float* Wb; float* out;
        if (row < NUM_REL) { tbl = rel_table + row*HID;            Wb = W_rt;          out = relP + row*D; }
        else               { tbl = time_table + (row-NUM_REL)*HID; Wb = W_rt + HID*D;  out = timP + (row-NUM_REL)*D; }
        float acc = 0.f;
        #pragma unroll
        for (int k = 0; k < HID; ++k) acc += tbl[k] * Wb[k*D + j];
        out[j] = acc;
    } else {
        int id = (b - 298)*256 + threadIdx.x;   // 0..6143
        if (id < 4096) {                 // W13 frags
            int mt = id >> 8;            // 0..15
            int s  = (id >> 6) & 3;
            int l  = id & 63;
            int m  = mt*16 + (l & 15);   // output col 0..255
            int kb = s*32 + (l >> 4)*8;
            unsigned short* dst = Wpk13 + ((size_t)(mt*4 + s)*64 + l)*8;
            #pragma unroll
            for (int j = 0; j < 8; ++j) {
                int k = kb + j;
                float v = (m < D) ? W_fc[(size_t)k*D + m]
                                  : W_fc[(size_t)(256 + k)*D + (m - D)];
                dst[j] = (unsigned short)bf_rne(v);
            }
        } else {                         // W2 frags
            int id2 = id - 4096;
            int mt = id2 >> 8;           // 0..7
            int s  = (id2 >> 6) & 3;
            int l  = id2 & 63;
            int m  = mt*16 + (l & 15);
            int kb = s*32 + (l >> 4)*8;
            unsigned short* dst = Wpk2 + ((size_t)(mt*4 + s)*64 + l)*8;
            #pragma unroll
            for (int j = 0; j < 8; ++j) {
                int k = kb + j;
                dst[j] = (unsigned short)bf_rne(W_fc[(size_t)(D + k)*D + m]);
            }
        }
    }
}

// ---------------------------------------------------------------------------
// Launch 3 — k_mm: scatter blocks BRESENHAM-INTERLEAVED among xw/t2 MFMA
// blocks so every CU hosts a latency-bound/compute-bound mix from t=0
// (round-4 lesson: front-loading the 1563 scatter blocks created a serial
// atomic phase with no MFMA overlap). Hs halved to 64*XPAD (17.4 KB) via
// 64-combo t2 tiles so LDS no longer binds occupancy.
// ---------------------------------------------------------------------------
__device__ __forceinline__ void xw_body(
        int xb, const float* __restrict__ x,
        const unsigned short* __restrict__ Wpk13,
        unsigned short* __restrict__ xW13bf, int n_nodes,
        unsigned short* Xs /* 64*XPAD */)
{
    int t = threadIdx.x;
    int nodeBase = xb*64;
    {   // stage X tile (fp32 -> bf16), 4 threads per node row
        int row = t >> 2;
        int k0  = (t & 3)*32;
        int node = nodeBase + row;
        unsigned short* dst = Xs + row*XPAD + k0;
        if (node < n_nodes) {
            const float4* src = (const float4*)(x + (size_t)node*D + k0);
            #pragma unroll
            for (int g = 0; g < 8; ++g) {
                float4 v = src[g];
                *(uint2*)(dst + g*4) = make_uint2(pk2(v.x, v.y), pk2(v.z, v.w));
            }
        } else {
            #pragma unroll
            for (int g = 0; g < 8; ++g)
                *(uint2*)(dst + g*4) = make_uint2(0u, 0u);
        }
    }
    __syncthreads();

    int w = t >> 6, l = t & 63;
    int li = l & 15, q = l >> 4;

    f32x4 acc[4][4];
    #pragma unroll
    for (int mi = 0; mi < 4; ++mi)
        #pragma unroll
        for (int ni = 0; ni < 4; ++ni) acc[mi][ni] = (f32x4){0.f,0.f,0.f,0.f};

    #pragma unroll 1
    for (int s = 0; s < 4; ++s) {
        short8 af[4], bf[4];
        #pragma unroll
        for (int mi = 0; mi < 4; ++mi) {
            int mt = w*4 + mi;
            af[mi] = *(const short8*)(Wpk13 + ((size_t)(mt*4 + s)*64 + l)*8);
        }
        #pragma unroll
        for (int ni = 0; ni < 4; ++ni)
            bf[ni] = *(const short8*)(Xs + (ni*16 + li)*XPAD + s*32 + q*8);
        #pragma unroll
        for (int mi = 0; mi < 4; ++mi)
            #pragma unroll
            for (int ni = 0; ni < 4; ++ni)
                acc[mi][ni] = __builtin_amdgcn_mfma_f32_16x16x32_bf16(
                                  af[mi], bf[ni], acc[mi][ni], 0, 0, 0);
    }
    #pragma unroll
    for (int ni = 0; ni < 4; ++ni) {
        int node = nodeBase + ni*16 + li;
        if (node >= n_nodes) continue;
        #pragma unroll
        for (int mi = 0; mi < 4; ++mi) {
            int col = w*64 + mi*16 + q*4;
            *(uint2*)(xW13bf + (size_t)node*256 + col) =
                make_uint2(pk2(acc[mi][ni][0], acc[mi][ni][1]),
                           pk2(acc[mi][ni][2], acc[mi][ni][3]));
        }
    }
}

__device__ __forceinline__ void t2_body(
        int tb, const float* __restrict__ relP, const float* __restrict__ timP,
        const float* __restrict__ b_rt, const unsigned short* __restrict__ Wpk2,
        unsigned short* __restrict__ T2bf,
        unsigned short* Hs /* 64*XPAD */)
{
    int t = threadIdx.x;
    int cBase = tb*64;
    {   // stage H tile: lrelu(relP+timP+b) -> bf16, 4 threads per row
        int r  = t >> 2;
        int hk = (t & 3)*32;
        int combo = cBase + r;
        if (combo >= NCOMB) combo = NCOMB - 1;
        int rr = combo / NUM_TS;
        int tt = combo - rr*NUM_TS;
        const float4* rv4 = (const float4*)(relP + (size_t)rr*D + hk);
        const float4* tv4 = (const float4*)(timP + (size_t)tt*D + hk);
        const float4* bv4 = (const float4*)(b_rt + hk);
        unsigned short* dst = Hs + r*XPAD + hk;
        #pragma unroll
        for (int g = 0; g < 8; ++g) {
            float4 rv = rv4[g], tv = tv4[g], bv = bv4[g];
            float v0 = lrelu(rv.x+tv.x+bv.x), v1 = lrelu(rv.y+tv.y+bv.y);
            float v2 = lrelu(rv.z+tv.z+bv.z), v3 = lrelu(rv.w+tv.w+bv.w);
            *(uint2*)(dst + g*4) = make_uint2(pk2(v0,v1), pk2(v2,v3));
        }
    }
    __syncthreads();

    int w = t >> 6, l = t & 63;
    int li = l & 15, q = l >> 4;

    f32x4 acc[2][4];
    #pragma unroll
    for (int mi = 0; mi < 2; ++mi)
        #pragma unroll
        for (int ni = 0; ni < 4; ++ni) acc[mi][ni] = (f32x4){0.f,0.f,0.f,0.f};

    #pragma unroll 1
    for (int s = 0; s < 4; ++s) {
        short8 af[2], bf[4];
        #pragma unroll
        for (int mi = 0; mi < 2; ++mi) {
            int mt = w*2 + mi;
            af[mi] = *(const short8*)(Wpk2 + ((size_t)(mt*4 + s)*64 + l)*8);
        }
        #pragma unroll
        for (int ni = 0; ni < 4; ++ni)
            bf[ni] = *(const short8*)(Hs + (ni*16 + li)*XPAD + s*32 + q*8);
        #pragma unroll
        for (int mi = 0; mi < 2; ++mi)
            #pragma unroll
            for (int ni = 0; ni < 4; ++ni)
                acc[mi][ni] = __builtin_amdgcn_mfma_f32_16x16x32_bf16(
                                  af[mi], bf[ni], acc[mi][ni], 0, 0, 0);
    }
    #pragma unroll
    for (int ni = 0; ni < 4; ++ni) {
        int combo = cBase + ni*16 + li;
        if (combo >= NCOMB) continue;
        #pragma unroll
        for (int mi = 0; mi < 2; ++mi) {
            int col = (w*2 + mi)*16 + q*4;
            *(uint2*)(T2bf + (size_t)combo*D + col) =
                make_uint2(pk2(acc[mi][ni][0], acc[mi][ni][1]),
                           pk2(acc[mi][ni][2], acc[mi][ni][3]));
        }
    }
}

__global__ __launch_bounds__(256, 3) void k_mm(
        const float* __restrict__ x, const unsigned short* __restrict__ Wpk13,
        unsigned short* __restrict__ xW13bf, int n_nodes,
        const float* __restrict__ relP, const float* __restrict__ timP,
        const float* __restrict__ b_rt, const unsigned short* __restrict__ Wpk2,
        unsigned short* __restrict__ T2bf,
        const int* __restrict__ edges, int n_edges,
        int* __restrict__ deg, int2* __restrict__ ebuf,
        int nsc, int nxw, int ntot)
{
    __shared__ __align__(16) unsigned short Hs[64*XPAD];  // 17.4 KB (union)
    int b = blockIdx.x;
    // Bresenham interleave: scatter block iff cumulative count increments.
    int cumCur  = (int)(((long long)b       * nsc) / ntot);
    int cumNext = (int)(((long long)(b + 1) * nsc) / ntot);
    if (cumNext > cumCur) {
        // edge bucket-scatter block #cumCur (latency-bound; co-resident with
        // MFMA blocks on every CU). deg zeroed by hipMemsetAsync (blit).
        int e = cumCur*256 + threadIdx.x;
        if (e < n_edges) {
            int4 ed = ((const int4*)edges)[e];
            int slot = atomicAdd(&deg[ed.y], 1);
            if (slot < MAXDEG)   // safety clamp; statistically never taken
                ebuf[(size_t)ed.y*MAXDEG + slot] = make_int2(ed.x, ed.z*NUM_TS + ed.w);
        }
    } else {
        int cidx = b - cumNext;
        if (cidx < nxw) {
            xw_body(cidx, x, Wpk13, xW13bf, n_nodes, Hs);
        } else {
            t2_body(cidx - nxw, relP, timP, b_rt, Wpk2, T2bf, Hs);
        }
    }
}

// ---------------------------------------------------------------------------
// Launch 4 — k_agg: 4 nodes per wave, 16 lanes per node, uint4 (16B) gathers.
// (unchanged — measured at the random-gather path floor ~42 µs)
// ---------------------------------------------------------------------------
__global__ __launch_bounds__(256) void k_agg(
        const int* __restrict__ deg, const int2* __restrict__ ebuf,
        const unsigned short* __restrict__ xW13bf,
        const unsigned short* __restrict__ T2bf,
        const float* __restrict__ b_fc,
        float* __restrict__ out, int n_nodes)
{
    int t    = threadIdx.x;
    int lane = t & 63;
    int g    = lane >> 4;             // node group within wave (0..3)
    int sub  = lane & 15;             // lane within group; covers cols sub*8..+7
    int node = blockIdx.x*16 + (t >> 6)*4 + g;
    bool valid = node < n_nodes;
    int nodeC  = valid ? node : n_nodes - 1;

    int dg  = deg[nodeC];
    int cnt = valid ? (dg < MAXDEG ? dg : MAXDEG) : 0;
    int cm1 = cnt > 0 ? cnt - 1 : 0;
    const int2* eb = ebuf + (size_t)nodeC * MAXDEG;

    // wave-max trip count (cnt is uniform within each 16-lane group)
    int cmax = cnt;
    cmax = max(cmax, __shfl_xor(cmax, 16));
    cmax = max(cmax, __shfl_xor(cmax, 32));

    // base = xW3[node] + b_fc for this lane's 8 cols
    float base[8];
    {
        uint4  w3  = *(const uint4*)&xW13bf[(size_t)nodeC*256 + 128 + sub*8];
        float4 blo = *(const float4*)&b_fc[sub*8];
        float4 bhi = *(const float4*)&b_fc[sub*8 + 4];
        base[0] = bf_lo(w3.x) + blo.x; base[1] = bf_hi(w3.x) + blo.y;
        base[2] = bf_lo(w3.y) + blo.z; base[3] = bf_hi(w3.y) + blo.w;
        base[4] = bf_lo(w3.z) + bhi.x; base[5] = bf_hi(w3.z) + bhi.y;
        base[6] = bf_lo(w3.w) + bhi.z; base[7] = bf_hi(w3.w) + bhi.w;
    }

    float acc[8];
    #pragma unroll
    for (int k = 0; k < 8; ++k) acc[k] = 0.f;

    const unsigned sMax = (unsigned)(n_nodes - 1);
    const unsigned cMax = (unsigned)(NCOMB - 1);

    for (int e = 0; e < cmax; e += 4) {
        // --- batch 1: index loads (independent, clamped in-bounds) ---
        int2 e0 = eb[min(e + 0, cm1)];
        int2 e1 = eb[min(e + 1, cm1)];
        int2 e2 = eb[min(e + 2, cm1)];
        int2 e3 = eb[min(e + 3, cm1)];
        // --- clamp gather targets (garbage-safe for masked slots) ---
        unsigned s0 = min((unsigned)e0.x, sMax), c0 = min((unsigned)e0.y, cMax);
        unsigned s1 = min((unsigned)e1.x, sMax), c1 = min((unsigned)e1.y, cMax);
        unsigned s2 = min((unsigned)e2.x, sMax), c2 = min((unsigned)e2.y, cMax);
        unsigned s3 = min((unsigned)e3.x, sMax), c3 = min((unsigned)e3.y, cMax);
        // --- batch 2: 8 independent 16B gathers ---
        uint4 S0 = *(const uint4*)&xW13bf[(size_t)s0*256 + sub*8];
        uint4 T0 = *(const uint4*)&T2bf  [(size_t)c0*D   + sub*8];
        uint4 S1 = *(const uint4*)&xW13bf[(size_t)s1*256 + sub*8];
        uint4 T1 = *(const uint4*)&T2bf  [(size_t)c1*D   + sub*8];
        uint4 S2 = *(const uint4*)&xW13bf[(size_t)s2*256 + sub*8];
        uint4 T2 = *(const uint4*)&T2bf  [(size_t)c2*D   + sub*8];
        uint4 S3 = *(const uint4*)&xW13bf[(size_t)s3*256 + sub*8];
        uint4 T3 = *(const uint4*)&T2bf  [(size_t)c3*D   + sub*8];
        // --- consume (cndmask-masked; no divergent control flow) ---
        bool m0 = (e + 0) < cnt, m1 = (e + 1) < cnt;
        bool m2 = (e + 2) < cnt, m3 = (e + 3) < cnt;
        #pragma unroll
        for (int w = 0; w < 4; ++w) {
            unsigned Sw0 = (&S0.x)[w], Tw0 = (&T0.x)[w];
            unsigned Sw1 = (&S1.x)[w], Tw1 = (&T1.x)[w];
            unsigned Sw2 = (&S2.x)[w], Tw2 = (&T2.x)[w];
            unsigned Sw3 = (&S3.x)[w], Tw3 = (&T3.x)[w];
            float v0l = lrelu(bf_lo(Sw0) + bf_lo(Tw0) + base[2*w]);
            float v0h = lrelu(bf_hi(Sw0) + bf_hi(Tw0) + base[2*w+1]);
            float v1l = lrelu(bf_lo(Sw1) + bf_lo(Tw1) + base[2*w]);
            float v1h = lrelu(bf_hi(Sw1) + bf_hi(Tw1) + base[2*w+1]);
            float v2l = lrelu(bf_lo(Sw2) + bf_lo(Tw2) + base[2*w]);
            float v2h = lrelu(bf_hi(Sw2) + bf_hi(Tw2) + base[2*w+1]);
            float v3l = lrelu(bf_lo(Sw3) + bf_lo(Tw3) + base[2*w]);
            float v3h = lrelu(bf_hi(Sw3) + bf_hi(Tw3) + base[2*w+1]);
            float a01l = (m0 ? v0l : 0.f) + (m1 ? v1l : 0.f);
            float a23l = (m2 ? v2l : 0.f) + (m3 ? v3l : 0.f);
            float a01h = (m0 ? v0h : 0.f) + (m1 ? v1h : 0.f);
            float a23h = (m2 ? v2h : 0.f) + (m3 ? v3h : 0.f);
            acc[2*w]   += a01l + a23l;
            acc[2*w+1] += a01h + a23h;
        }
    }

    if (!valid) return;
    float inv = 1.f / fmaxf((float)dg, 1.f);
    float4 o0 = make_float4(acc[0]*inv, acc[1]*inv, acc[2]*inv, acc[3]*inv);
    float4 o1 = make_float4(acc[4]*inv, acc[5]*inv, acc[6]*inv, acc[7]*inv);
    *(float4*)&out[(size_t)node*D + sub*8]     = o0;
    *(float4*)&out[(size_t)node*D + sub*8 + 4] = o1;
}

// ---------------------------------------------------------------------------
extern "C" void kernel_launch(void* const* d_in, const int* in_sizes, int n_in,
                              void* d_out, int out_size, void* d_ws, size_t ws_size,
                              hipStream_t stream)
{
    const float* x          = (const float*)d_in[0];
    const float* rel_table  = (const float*)d_in[1];
    const float* time_table = (const float*)d_in[2];
    const float* W_rt       = (const float*)d_in[3];
    const float* b_rt       = (const float*)d_in[4];
    const float* W_fc       = (const float*)d_in[5];
    const float* b_fc       = (const float*)d_in[6];
    const int*   edges      = (const int*)d_in[7];

    int n_nodes = in_sizes[0] / D;   // 50000
    int n_edges = in_sizes[7] / 4;   // 400000
    int nblkE   = (n_edges + 255) / 256;   // 1563
    int nxw     = (n_nodes + 63) / 64;     // 782
    int nt2     = (NCOMB + 63) / 64;       // 1312
    int ntot    = nblkE + nxw + nt2;       // 3657

    char* ws = (char*)d_ws;
    size_t off = 0;
    auto alloc = [&](size_t bytes) -> void* {
        void* p = ws + off; off += (bytes + 255) & ~(size_t)255; return p;
    };
    unsigned short* xW13bf = (unsigned short*)alloc((size_t)n_nodes * 256 * 2); // 25.6 MB
    unsigned short* T2bf   = (unsigned short*)alloc((size_t)NCOMB * D * 2);     // 21.5 MB
    unsigned short* Wpk13  = (unsigned short*)alloc((size_t)16*4*64*8 * 2);     // 64 KB
    unsigned short* Wpk2   = (unsigned short*)alloc((size_t)8*4*64*8 * 2);      // 32 KB
    float* relP   = (float*)alloc((size_t)NUM_REL * D * sizeof(float));
    float* timP   = (float*)alloc((size_t)NUM_TS * D * sizeof(float));
    int*   deg    = (int*)alloc((size_t)n_nodes * sizeof(int));
    int2*  ebuf   = (int2*)alloc((size_t)n_nodes * MAXDEG * sizeof(int2));      // 25.6 MB
    if (off > ws_size)
        fprintf(stderr, "kernel_launch: workspace too small: need %zu, have %zu\n", off, ws_size);

    hipMemsetAsync(deg, 0, (size_t)n_nodes * sizeof(int), stream);

    k_prep<<<322, 256, 0, stream>>>(rel_table, time_table, W_rt, W_fc,
                                    relP, timP, Wpk13, Wpk2);
    k_mm  <<<ntot, 256, 0, stream>>>(x, Wpk13, xW13bf, n_nodes,
                                     relP, timP, b_rt, Wpk2, T2bf,
                                     edges, n_edges, deg, ebuf,
                                     nblkE, nxw, ntot);
    k_agg <<<(n_nodes + 15)/16, 256, 0, stream>>>(deg, ebuf, xW13bf, T2bf,
                                                  b_fc, (float*)d_out, n_nodes);
}